// Round 18
// baseline (167.157 us; speedup 1.0000x reference)
//
#include <hip/hip_runtime.h>

#define B_ 32
#define C_ 512
#define HW_ 4096
#define N_ 80

typedef __bf16 bf16x8 __attribute__((ext_vector_type(8)));
typedef __bf16 bf16x4 __attribute__((ext_vector_type(4)));
typedef float f32x4 __attribute__((ext_vector_type(4)));
typedef unsigned short u16x8 __attribute__((ext_vector_type(8)));

__device__ __forceinline__ void gload_lds16(const void* g, void* l) {
  __builtin_amdgcn_global_load_lds((const __attribute__((address_space(1))) void*)g,
                                   (__attribute__((address_space(3))) void*)l, 16, 0, 0);
}

#define VMCNT(n) asm volatile("s_waitcnt vmcnt(" #n ")" ::: "memory")
#define SBAR() asm volatile("s_barrier" ::: "memory")

// ---------------------------------------------------------------------------
// K0: refragment W -> Wfrag bf16 (MFMA B-operand unit layout) AND zero denom.
// ---------------------------------------------------------------------------
__global__ __launch_bounds__(256) void k0_wfrag(const float* __restrict__ W,
                                                __bf16* __restrict__ Wfrag,
                                                float* __restrict__ denom) {
  const int t = blockIdx.x * 256 + threadIdx.x;
  if (t < B_ * N_) denom[t] = 0.f;
  if (t >= 16 * 5 * 64) return;
  const int cs = t / 320, rem = t % 320;
  const int nf = rem >> 6, lane = rem & 63;
  const int n = nf * 16 + (lane & 15);
  const int c = cs * 32 + (lane >> 4) * 8;
  const float* wp = W + (size_t)n * C_ + c;
  bf16x8 v;
#pragma unroll
  for (int i = 0; i < 8; ++i) v[i] = (__bf16)wp[i];
  *(bf16x8*)(Wfrag + (size_t)t * 8) = v;
}

// ---------------------------------------------------------------------------
// K1: Efrag = exp-fragments in K3's B-operand unit order; denom += row sums.
// FROZEN (R17; core measured 6.4 TB/s). Grid (HW/128, B), 3 blocks/CU.
// ---------------------------------------------------------------------------
#define K1_STAGE(CS, SLOT)                                                      \
  {                                                                             \
    _Pragma("unroll") for (int j = 0; j < 4; ++j) {                             \
      const int d = j * 256 + tid;                                              \
      const int r = d >> 5, p = d & 31;                                         \
      gload_lds16(fb + (size_t)((CS)*32 + r) * HW_ + htile0 + p * 4,            \
                  (char*)tile + (SLOT)*16384 + (j * 256 + wave * 64) * 16);     \
    }                                                                           \
  }

#define K1_WLOAD(W, CS)                                                         \
  {                                                                             \
    _Pragma("unroll") for (int nf = 0; nf < 5; ++nf)                            \
        W[nf] = *(const u16x8*)(Wfrag + ((size_t)((CS)*5 + nf) * 64 + lane) * 8); \
  }

#define K1_COMPUTE(T, WU)                                                       \
  {                                                                             \
    const float* tb = (const float*)((char*)tile + ((T) % 3) * 16384);          \
    bf16x8 afr[2];                                                              \
    _Pragma("unroll") for (int hf = 0; hf < 2; ++hf) {                          \
      const int col = wave * 32 + hf * 16 + l16;                                \
      _Pragma("unroll") for (int i = 0; i < 8; ++i)                             \
          afr[hf][i] = (__bf16)tb[(quad * 8 + i) * 128 + col];                  \
    }                                                                           \
    _Pragma("unroll") for (int nf = 0; nf < 5; ++nf) {                          \
      const bf16x8 bfr = __builtin_bit_cast(bf16x8, WU[nf]);                    \
      acc[0][nf] = __builtin_amdgcn_mfma_f32_16x16x32_bf16(afr[0], bfr, acc[0][nf], 0, 0, 0); \
      acc[1][nf] = __builtin_amdgcn_mfma_f32_16x16x32_bf16(afr[1], bfr, acc[1][nf], 0, 0, 0); \
    }                                                                           \
  }

#define K1_ITER(T, WU, WL)                                                      \
  {                                                                             \
    VMCNT(9); SBAR();                                                           \
    K1_WLOAD(WL, (T) + 1);                                                      \
    if ((T) + 2 < 16) K1_STAGE((T) + 2, ((T) + 2) % 3);                         \
    K1_COMPUTE(T, WU);                                                          \
  }

__global__ __launch_bounds__(256, 3) void k1_logits(const float* __restrict__ feats,
                                                    const __bf16* __restrict__ Wfrag,
                                                    __bf16* __restrict__ Efrag,
                                                    float* __restrict__ denom) {
  __shared__ float tile[3][32 * 128];  // 48 KB
  const int tid = threadIdx.x;
  const int lane = tid & 63, wave = tid >> 6;
  const int quad = lane >> 4, l16 = lane & 15;
  const int b = blockIdx.y;
  const int htile0 = blockIdx.x * 128;
  const float* fb = feats + (size_t)b * (C_ * HW_);

  const f32x4 zero = {0.f, 0.f, 0.f, 0.f};
  f32x4 acc[2][5];
#pragma unroll
  for (int hf = 0; hf < 2; ++hf)
#pragma unroll
    for (int nf = 0; nf < 5; ++nf) acc[hf][nf] = zero;

  u16x8 wfA[5], wfB[5];
  K1_STAGE(0, 0);
  K1_WLOAD(wfA, 0);
  K1_STAGE(1, 1);

  for (int t = 0; t < 14; t += 2) {
    K1_ITER(t, wfA, wfB);
    K1_ITER(t + 1, wfB, wfA);
  }
  K1_ITER(14, wfA, wfB);
  VMCNT(5); SBAR();
  K1_COMPUTE(15, wfB);

  // Epilogue: exp -> per-wave scratch bounce -> Efrag units + denom atomics.
  __bf16* sw = (__bf16*)((char*)tile + 16384 + wave * 2304);
  const int hc = (htile0 >> 5) + wave;  // this wave's global 32-h chunk
#pragma unroll
  for (int nf = 0; nf < 5; ++nf) {
    const int n = nf * 16 + l16;
    float s = 0.f;
#pragma unroll
    for (int hf = 0; hf < 2; ++hf) {
      bf16x4 pk;
#pragma unroll
      for (int j = 0; j < 4; ++j) {
        const float e = __expf(acc[hf][nf][j]);
        s += e;
        pk[j] = (__bf16)e;
      }
      *(bf16x4*)&sw[l16 * 72 + hf * 16 + quad * 4] = pk;
    }
    s += __shfl_xor(s, 16);
    s += __shfl_xor(s, 32);
    if (lane < 16) atomicAdd(denom + b * N_ + nf * 16 + lane, s);
    const bf16x8 u = *(const bf16x8*)&sw[l16 * 72 + quad * 8];
    *(bf16x8*)(Efrag + (((size_t)(b * 128 + hc) * 5 + nf) * 64 + lane) * 8) = u;
  }
}

// ---------------------------------------------------------------------------
// K3-D: out[b][n][c] = (sum_h E * feats) / denom.  (R17 structure)
// ONLY CHANGE vs R17: __launch_bounds__(256, 5) -> 5 blocks/CU (LDS
// 5 x 32 KB = 160 KB exact), 20 waves/CU. VGPR cap ~102; inventory ~105 --
// single-variable occupancy experiment.
// ---------------------------------------------------------------------------
#define K3_STAGE(T, SLOT)                                                       \
  {                                                                             \
    _Pragma("unroll") for (int j = 0; j < 2; ++j) {                             \
      const int d = j * 256 + tid;                                              \
      const int r = d >> 5, p = d & 31;                                         \
      gload_lds16(fb + (size_t)(c0 + r) * HW_ + (T)*128 + ((p ^ r) << 2),       \
                  (char*)fA + (SLOT)*8192 + (j * 256 + wave * 64) * 16);        \
    }                                                                           \
  }

#define K3_BFRAG(DST, T)                                                        \
  {                                                                             \
    _Pragma("unroll") for (int ks_ = 0; ks_ < 4; ++ks_)                         \
    _Pragma("unroll") for (int f_ = 0; f_ < 2; ++f_)                            \
      if (f_ < nfcnt)                                                           \
        DST[ks_][f_] = *(const u16x8*)(Efrag +                                  \
            (((size_t)(b * 128 + (T)*4 + ks_) * 5 + nfbase + f_) * 64 + lane) * 8); \
  }

#define K3_COMPUTE(T, BFS)                                                      \
  {                                                                             \
    const float* A = (const float*)((char*)fA + ((T)&3) * 8192);                \
    _Pragma("unroll") for (int ks_ = 0; ks_ < 4; ++ks_) {                       \
      const int u0 = (ks_ * 8 + quad * 2) ^ l16;                                \
      const int u1 = (ks_ * 8 + quad * 2 + 1) ^ l16;                            \
      const f32x4 va = *(const f32x4*)&A[l16 * 128 + u0 * 4];                   \
      const f32x4 vb = *(const f32x4*)&A[l16 * 128 + u1 * 4];                   \
      bf16x8 af;                                                                \
      af[0] = (__bf16)va[0]; af[1] = (__bf16)va[1];                             \
      af[2] = (__bf16)va[2]; af[3] = (__bf16)va[3];                             \
      af[4] = (__bf16)vb[0]; af[5] = (__bf16)vb[1];                             \
      af[6] = (__bf16)vb[2]; af[7] = (__bf16)vb[3];                             \
      _Pragma("unroll") for (int f_ = 0; f_ < 2; ++f_)                          \
        if (f_ < nfcnt) {                                                       \
          const bf16x8 bfr = __builtin_bit_cast(bf16x8, BFS[ks_][f_]);          \
          acc[f_] = __builtin_amdgcn_mfma_f32_16x16x32_bf16(af, bfr, acc[f_], 0, 0, 0); \
        }                                                                       \
    }                                                                           \
  }

#define K3_ITER(T, USE, LOADDST)                                                \
  {                                                                             \
    VMCNT(2); SBAR();                                                           \
    K3_BFRAG(LOADDST, (T) + 1);                                                 \
    if ((T) + 3 < 32) K3_STAGE((T) + 3, ((T) + 3) & 3);                         \
    K3_COMPUTE(T, USE);                                                         \
  }

__global__ __launch_bounds__(256, 5) void k3_pool(const float* __restrict__ feats,
                                                  const __bf16* __restrict__ Efrag,
                                                  const float* __restrict__ denom,
                                                  float* __restrict__ out) {
  __shared__ float fA[4 * 16 * 128];  // 32 KB (4 slots x 8 KB)
  const int tid = threadIdx.x;
  const int lane = tid & 63, wave = tid >> 6;
  const int quad = lane >> 4, l16 = lane & 15;
  const int nfbase = (wave == 0) ? 0 : (wave + 1);
  const int nfcnt = (wave == 0) ? 2 : 1;

  // XCD-chunked remap (bijective: 1024 = 8 * 128): 4 b's per XCD.
  const int wg = blockIdx.x;
  const int nid = (wg & 7) * 128 + (wg >> 3);
  const int b = nid >> 5, cx = nid & 31;
  const int c0 = cx * 16;

  const float* fb = feats + (size_t)b * (C_ * HW_);
  const f32x4 zero = {0.f, 0.f, 0.f, 0.f};

  f32x4 acc[2];
  acc[0] = zero;
  acc[1] = zero;

  u16x8 bfA[4][2], bfB[4][2];
  K3_BFRAG(bfA, 0);
  K3_STAGE(0, 0);
  K3_STAGE(1, 1);
  K3_STAGE(2, 2);

  for (int t = 0; t < 28; t += 2) {
    K3_ITER(t, bfA, bfB);
    K3_ITER(t + 1, bfB, bfA);
  }
  K3_ITER(28, bfA, bfB);
  VMCNT(2); SBAR();
  K3_BFRAG(bfA, 30);
  K3_COMPUTE(29, bfB);
  VMCNT(0); SBAR();
  K3_BFRAG(bfB, 31);
  K3_COMPUTE(30, bfA);
  VMCNT(0); SBAR();
  K3_COMPUTE(31, bfB);

#pragma unroll
  for (int f = 0; f < 2; ++f) {
    if (f >= nfcnt) break;
    const int n = (nfbase + f) * 16 + l16;
    const float r = 1.0f / denom[b * N_ + n];
    float4 v;
    v.x = acc[f][0] * r; v.y = acc[f][1] * r;
    v.z = acc[f][2] * r; v.w = acc[f][3] * r;
    *(float4*)(out + (size_t)(b * N_ + n) * C_ + c0 + quad * 4) = v;
  }
}

extern "C" void kernel_launch(void* const* d_in, const int* in_sizes, int n_in,
                              void* d_out, int out_size, void* d_ws, size_t ws_size,
                              hipStream_t stream) {
  (void)in_sizes; (void)n_in; (void)out_size; (void)ws_size;
  const float* feats = (const float*)d_in[0];
  const float* Wm = (const float*)d_in[1];
  float* out = (float*)d_out;

  __bf16* Efrag = (__bf16*)d_ws;                   // 21 MB
  __bf16* Wfrag = Efrag + (size_t)B_ * N_ * HW_;   // 80 KB
  float* denom = (float*)(Wfrag + 16 * 5 * 64 * 8);  // 10 KB

  hipLaunchKernelGGL(k0_wfrag, dim3(20), dim3(256), 0, stream, Wm, Wfrag, denom);
  hipLaunchKernelGGL(k1_logits, dim3(HW_ / 128, B_), dim3(256), 0, stream, feats, Wfrag, Efrag, denom);
  hipLaunchKernelGGL(k3_pool, dim3(1024), dim3(256), 0, stream, feats, Efrag, denom, out);
}

// Round 19
// 113.012 us; speedup vs baseline: 1.4791x; 1.4791x over previous
//
#include <hip/hip_runtime.h>

#define B_ 32
#define C_ 512
#define HW_ 4096
#define N_ 80

typedef __bf16 bf16x8 __attribute__((ext_vector_type(8)));
typedef __bf16 bf16x4 __attribute__((ext_vector_type(4)));
typedef float f32x4 __attribute__((ext_vector_type(4)));
typedef unsigned short u16x8 __attribute__((ext_vector_type(8)));

__device__ __forceinline__ void gload_lds16(const void* g, void* l) {
  __builtin_amdgcn_global_load_lds((const __attribute__((address_space(1))) void*)g,
                                   (__attribute__((address_space(3))) void*)l, 16, 0, 0);
}

#define VMCNT(n) asm volatile("s_waitcnt vmcnt(" #n ")" ::: "memory")
#define SBAR() asm volatile("s_barrier" ::: "memory")

// ---------------------------------------------------------------------------
// K0: refragment W -> Wfrag bf16 (MFMA B-operand unit layout) AND zero denom.
// ---------------------------------------------------------------------------
__global__ __launch_bounds__(256) void k0_wfrag(const float* __restrict__ W,
                                                __bf16* __restrict__ Wfrag,
                                                float* __restrict__ denom) {
  const int t = blockIdx.x * 256 + threadIdx.x;
  if (t < B_ * N_) denom[t] = 0.f;
  if (t >= 16 * 5 * 64) return;
  const int cs = t / 320, rem = t % 320;
  const int nf = rem >> 6, lane = rem & 63;
  const int n = nf * 16 + (lane & 15);
  const int c = cs * 32 + (lane >> 4) * 8;
  const float* wp = W + (size_t)n * C_ + c;
  bf16x8 v;
#pragma unroll
  for (int i = 0; i < 8; ++i) v[i] = (__bf16)wp[i];
  *(bf16x8*)(Wfrag + (size_t)t * 8) = v;
}

// ---------------------------------------------------------------------------
// K1: Efrag = exp-fragments in K3's B-operand unit order; denom += row sums.
// FROZEN (measured 6.4 TB/s = HBM roofline). Grid (HW/128, B), 3 blocks/CU.
// ---------------------------------------------------------------------------
#define K1_STAGE(CS, SLOT)                                                      \
  {                                                                             \
    _Pragma("unroll") for (int j = 0; j < 4; ++j) {                             \
      const int d = j * 256 + tid;                                              \
      const int r = d >> 5, p = d & 31;                                         \
      gload_lds16(fb + (size_t)((CS)*32 + r) * HW_ + htile0 + p * 4,            \
                  (char*)tile + (SLOT)*16384 + (j * 256 + wave * 64) * 16);     \
    }                                                                           \
  }

#define K1_WLOAD(W, CS)                                                         \
  {                                                                             \
    _Pragma("unroll") for (int nf = 0; nf < 5; ++nf)                            \
        W[nf] = *(const u16x8*)(Wfrag + ((size_t)((CS)*5 + nf) * 64 + lane) * 8); \
  }

#define K1_COMPUTE(T, WU)                                                       \
  {                                                                             \
    const float* tb = (const float*)((char*)tile + ((T) % 3) * 16384);          \
    bf16x8 afr[2];                                                              \
    _Pragma("unroll") for (int hf = 0; hf < 2; ++hf) {                          \
      const int col = wave * 32 + hf * 16 + l16;                                \
      _Pragma("unroll") for (int i = 0; i < 8; ++i)                             \
          afr[hf][i] = (__bf16)tb[(quad * 8 + i) * 128 + col];                  \
    }                                                                           \
    _Pragma("unroll") for (int nf = 0; nf < 5; ++nf) {                          \
      const bf16x8 bfr = __builtin_bit_cast(bf16x8, WU[nf]);                    \
      acc[0][nf] = __builtin_amdgcn_mfma_f32_16x16x32_bf16(afr[0], bfr, acc[0][nf], 0, 0, 0); \
      acc[1][nf] = __builtin_amdgcn_mfma_f32_16x16x32_bf16(afr[1], bfr, acc[1][nf], 0, 0, 0); \
    }                                                                           \
  }

#define K1_ITER(T, WU, WL)                                                      \
  {                                                                             \
    VMCNT(9); SBAR();                                                           \
    K1_WLOAD(WL, (T) + 1);                                                      \
    if ((T) + 2 < 16) K1_STAGE((T) + 2, ((T) + 2) % 3);                         \
    K1_COMPUTE(T, WU);                                                          \
  }

__global__ __launch_bounds__(256, 3) void k1_logits(const float* __restrict__ feats,
                                                    const __bf16* __restrict__ Wfrag,
                                                    __bf16* __restrict__ Efrag,
                                                    float* __restrict__ denom) {
  __shared__ float tile[3][32 * 128];  // 48 KB
  const int tid = threadIdx.x;
  const int lane = tid & 63, wave = tid >> 6;
  const int quad = lane >> 4, l16 = lane & 15;
  const int b = blockIdx.y;
  const int htile0 = blockIdx.x * 128;
  const float* fb = feats + (size_t)b * (C_ * HW_);

  const f32x4 zero = {0.f, 0.f, 0.f, 0.f};
  f32x4 acc[2][5];
#pragma unroll
  for (int hf = 0; hf < 2; ++hf)
#pragma unroll
    for (int nf = 0; nf < 5; ++nf) acc[hf][nf] = zero;

  u16x8 wfA[5], wfB[5];
  K1_STAGE(0, 0);
  K1_WLOAD(wfA, 0);
  K1_STAGE(1, 1);

  for (int t = 0; t < 14; t += 2) {
    K1_ITER(t, wfA, wfB);
    K1_ITER(t + 1, wfB, wfA);
  }
  K1_ITER(14, wfA, wfB);
  VMCNT(5); SBAR();
  K1_COMPUTE(15, wfB);

  // Epilogue: exp -> per-wave scratch bounce -> Efrag units + denom atomics.
  __bf16* sw = (__bf16*)((char*)tile + 16384 + wave * 2304);
  const int hc = (htile0 >> 5) + wave;  // this wave's global 32-h chunk
#pragma unroll
  for (int nf = 0; nf < 5; ++nf) {
    const int n = nf * 16 + l16;
    float s = 0.f;
#pragma unroll
    for (int hf = 0; hf < 2; ++hf) {
      bf16x4 pk;
#pragma unroll
      for (int j = 0; j < 4; ++j) {
        const float e = __expf(acc[hf][nf][j]);
        s += e;
        pk[j] = (__bf16)e;
      }
      *(bf16x4*)&sw[l16 * 72 + hf * 16 + quad * 4] = pk;
    }
    s += __shfl_xor(s, 16);
    s += __shfl_xor(s, 32);
    if (lane < 16) atomicAdd(denom + b * N_ + nf * 16 + lane, s);
    const bf16x8 u = *(const bf16x8*)&sw[l16 * 72 + quad * 8];
    *(bf16x8*)(Efrag + (((size_t)(b * 128 + hc) * 5 + nf) * 64 + lane) * 8) = u;
  }
}

// ---------------------------------------------------------------------------
// K3-D: out[b][n][c] = (sum_h E * feats) / denom.  R17 CHAMPION, exact:
// __launch_bounds__(256, 4) -> 4 blocks/CU = 16 waves/CU, no VGPR spill
// (R18's (256,5) spilled: 167 us). feats f32 LDS [16c][128h]/slot, XOR
// src-swizzle p^=r, 4 slots = 32 KB. Coalesced register B-prefetch from
// Efrag (named sets), depth-1. FIFO iter: [vmcnt(2); bar; BFRAG(t+1);
// STAGE(t+3); compute(t)]. Grid 1024 flat, bijective XCD remap.
// ---------------------------------------------------------------------------
#define K3_STAGE(T, SLOT)                                                       \
  {                                                                             \
    _Pragma("unroll") for (int j = 0; j < 2; ++j) {                             \
      const int d = j * 256 + tid;                                              \
      const int r = d >> 5, p = d & 31;                                         \
      gload_lds16(fb + (size_t)(c0 + r) * HW_ + (T)*128 + ((p ^ r) << 2),       \
                  (char*)fA + (SLOT)*8192 + (j * 256 + wave * 64) * 16);        \
    }                                                                           \
  }

#define K3_BFRAG(DST, T)                                                        \
  {                                                                             \
    _Pragma("unroll") for (int ks_ = 0; ks_ < 4; ++ks_)                         \
    _Pragma("unroll") for (int f_ = 0; f_ < 2; ++f_)                            \
      if (f_ < nfcnt)                                                           \
        DST[ks_][f_] = *(const u16x8*)(Efrag +                                  \
            (((size_t)(b * 128 + (T)*4 + ks_) * 5 + nfbase + f_) * 64 + lane) * 8); \
  }

#define K3_COMPUTE(T, BFS)                                                      \
  {                                                                             \
    const float* A = (const float*)((char*)fA + ((T)&3) * 8192);                \
    _Pragma("unroll") for (int ks_ = 0; ks_ < 4; ++ks_) {                       \
      const int u0 = (ks_ * 8 + quad * 2) ^ l16;                                \
      const int u1 = (ks_ * 8 + quad * 2 + 1) ^ l16;                            \
      const f32x4 va = *(const f32x4*)&A[l16 * 128 + u0 * 4];                   \
      const f32x4 vb = *(const f32x4*)&A[l16 * 128 + u1 * 4];                   \
      bf16x8 af;                                                                \
      af[0] = (__bf16)va[0]; af[1] = (__bf16)va[1];                             \
      af[2] = (__bf16)va[2]; af[3] = (__bf16)va[3];                             \
      af[4] = (__bf16)vb[0]; af[5] = (__bf16)vb[1];                             \
      af[6] = (__bf16)vb[2]; af[7] = (__bf16)vb[3];                             \
      _Pragma("unroll") for (int f_ = 0; f_ < 2; ++f_)                          \
        if (f_ < nfcnt) {                                                       \
          const bf16x8 bfr = __builtin_bit_cast(bf16x8, BFS[ks_][f_]);          \
          acc[f_] = __builtin_amdgcn_mfma_f32_16x16x32_bf16(af, bfr, acc[f_], 0, 0, 0); \
        }                                                                       \
    }                                                                           \
  }

#define K3_ITER(T, USE, LOADDST)                                                \
  {                                                                             \
    VMCNT(2); SBAR();                                                           \
    K3_BFRAG(LOADDST, (T) + 1);                                                 \
    if ((T) + 3 < 32) K3_STAGE((T) + 3, ((T) + 3) & 3);                         \
    K3_COMPUTE(T, USE);                                                         \
  }

__global__ __launch_bounds__(256, 4) void k3_pool(const float* __restrict__ feats,
                                                  const __bf16* __restrict__ Efrag,
                                                  const float* __restrict__ denom,
                                                  float* __restrict__ out) {
  __shared__ float fA[4 * 16 * 128];  // 32 KB (4 slots x 8 KB)
  const int tid = threadIdx.x;
  const int lane = tid & 63, wave = tid >> 6;
  const int quad = lane >> 4, l16 = lane & 15;
  const int nfbase = (wave == 0) ? 0 : (wave + 1);
  const int nfcnt = (wave == 0) ? 2 : 1;

  // XCD-chunked remap (bijective: 1024 = 8 * 128): 4 b's per XCD.
  const int wg = blockIdx.x;
  const int nid = (wg & 7) * 128 + (wg >> 3);
  const int b = nid >> 5, cx = nid & 31;
  const int c0 = cx * 16;

  const float* fb = feats + (size_t)b * (C_ * HW_);
  const f32x4 zero = {0.f, 0.f, 0.f, 0.f};

  f32x4 acc[2];
  acc[0] = zero;
  acc[1] = zero;

  u16x8 bfA[4][2], bfB[4][2];
  K3_BFRAG(bfA, 0);
  K3_STAGE(0, 0);
  K3_STAGE(1, 1);
  K3_STAGE(2, 2);

  for (int t = 0; t < 28; t += 2) {
    K3_ITER(t, bfA, bfB);
    K3_ITER(t + 1, bfB, bfA);
  }
  K3_ITER(28, bfA, bfB);
  VMCNT(2); SBAR();
  K3_BFRAG(bfA, 30);
  K3_COMPUTE(29, bfB);
  VMCNT(0); SBAR();
  K3_BFRAG(bfB, 31);
  K3_COMPUTE(30, bfA);
  VMCNT(0); SBAR();
  K3_COMPUTE(31, bfB);

#pragma unroll
  for (int f = 0; f < 2; ++f) {
    if (f >= nfcnt) break;
    const int n = (nfbase + f) * 16 + l16;
    const float r = 1.0f / denom[b * N_ + n];
    float4 v;
    v.x = acc[f][0] * r; v.y = acc[f][1] * r;
    v.z = acc[f][2] * r; v.w = acc[f][3] * r;
    *(float4*)(out + (size_t)(b * N_ + n) * C_ + c0 + quad * 4) = v;
  }
}

extern "C" void kernel_launch(void* const* d_in, const int* in_sizes, int n_in,
                              void* d_out, int out_size, void* d_ws, size_t ws_size,
                              hipStream_t stream) {
  (void)in_sizes; (void)n_in; (void)out_size; (void)ws_size;
  const float* feats = (const float*)d_in[0];
  const float* Wm = (const float*)d_in[1];
  float* out = (float*)d_out;

  __bf16* Efrag = (__bf16*)d_ws;                   // 21 MB
  __bf16* Wfrag = Efrag + (size_t)B_ * N_ * HW_;   // 80 KB
  float* denom = (float*)(Wfrag + 16 * 5 * 64 * 8);  // 10 KB

  hipLaunchKernelGGL(k0_wfrag, dim3(20), dim3(256), 0, stream, Wm, Wfrag, denom);
  hipLaunchKernelGGL(k1_logits, dim3(HW_ / 128, B_), dim3(256), 0, stream, feats, Wfrag, Efrag, denom);
  hipLaunchKernelGGL(k3_pool, dim3(1024), dim3(256), 0, stream, feats, Efrag, denom, out);
}